// Round 6
// baseline (8137.502 us; speedup 1.0000x reference)
//
#include <hip/hip_runtime.h>
#include <hip/hip_bf16.h>
#include <hip/hip_fp16.h>

// ===========================================================================
// CSR build
// ===========================================================================
__global__ void hist_kernel(const int* __restrict__ rows, int* __restrict__ counts, int E) {
    int i = blockIdx.x * blockDim.x + threadIdx.x;
    if (i < E) atomicAdd(&counts[rows[i]], 1);
}

__global__ void scan_kernel(const int* __restrict__ counts, int* __restrict__ row_ptr, int V) {
    __shared__ int wsum[4];
    __shared__ int s_carry;
    int t = threadIdx.x;           // 256 threads
    int lane = t & 63, w = t >> 6;
    if (t == 0) { s_carry = 0; row_ptr[0] = 0; }
    __syncthreads();
    for (int base = 0; base < V; base += 256) {
        int i = base + t;
        int x = (i < V) ? counts[i] : 0;
        #pragma unroll
        for (int d = 1; d < 64; d <<= 1) {
            int y = __shfl_up(x, d);
            if (lane >= d) x += y;
        }
        if (lane == 63) wsum[w] = x;
        __syncthreads();
        int wo = 0;
        for (int j = 0; j < w; ++j) wo += wsum[j];
        int total = wsum[0] + wsum[1] + wsum[2] + wsum[3];
        if (i < V) row_ptr[i + 1] = s_carry + wo + x;
        __syncthreads();
        if (t == 0) s_carry += total;
        __syncthreads();
    }
}

__global__ void init_cursor_kernel(const int* __restrict__ row_ptr, int* __restrict__ cursor, int V) {
    int i = blockIdx.x * blockDim.x + threadIdx.x;
    if (i < V) cursor[i] = row_ptr[i];
}

__global__ void scatter_kernel(const int* __restrict__ rows, const int* __restrict__ cols,
                               const float* __restrict__ vals, int* __restrict__ cursor,
                               int* __restrict__ cols_s, float* __restrict__ vals_s, int E) {
    int i = blockIdx.x * blockDim.x + threadIdx.x;
    if (i < E) {
        int r = rows[i];
        int p = atomicAdd(&cursor[r], 1);
        cols_s[p] = cols[i];
        vals_s[p] = vals[i];
    }
}

// ===========================================================================
// transpose input (B,16,V) fp32 -> (V, B*16) fp16.  i = v*128 + (b*16+c)
// ===========================================================================
__global__ void transpose_in_kernel(const float* __restrict__ x, __half* __restrict__ X, int V) {
    int total = V * 128;
    for (int i = blockIdx.x * blockDim.x + threadIdx.x; i < total; i += gridDim.x * blockDim.x) {
        int v = i >> 7;
        int t = i & 127;          // t = b*16 + c
        X[i] = __float2half(x[t * V + v]);
    }
}

// ===========================================================================
// SpMM over half2 lanes:  dst[v,:] = sum_e vals[e]*src[cols[e],:]   (prev==null)
//                         dst[v,:] = 2*that - prev[v,:]             (prev!=null)
// prev may alias dst (same-thread read-before-write; no restrict on dst/prev).
// blockDim = BC/2 (pairs of channels), grid = V.
// ===========================================================================
__global__ __launch_bounds__(256) void spmm_kernel(
    const int* __restrict__ row_ptr, const int* __restrict__ cols,
    const float* __restrict__ vals,
    const __half2* __restrict__ src, __half2* dst, const __half2* prev) {
    int v = blockIdx.x;
    int t = threadIdx.x;
    int W = blockDim.x;                 // = BC/2
    float p0 = 0.f, p1 = 0.f;
    bool hasp = (prev != nullptr);
    if (hasp) {
        float2 pf = __half22float2(prev[(size_t)v * W + t]);   // load BEFORE store
        p0 = pf.x; p1 = pf.y;
    }
    int e0 = row_ptr[v], e1 = row_ptr[v + 1];
    float a0 = 0.f, a1 = 0.f;
    for (int e = e0; e < e1; ++e) {
        float wv = vals[e];
        float2 g = __half22float2(src[(size_t)cols[e] * W + t]);
        a0 += wv * g.x;
        a1 += wv * g.y;
    }
    if (hasp) { a0 = 2.f * a0 - p0; a1 = 2.f * a1 - p1; }
    dst[(size_t)v * W + t] = __floats2half2_rn(a0, a1);
}

// ===========================================================================
// mix: ACC[v,b,co] (+)= sum_ci in[v,b,ci] * W[ci*Cout+co] (+bias)
// in: fp16 features; ACC: fp32. in != ACC. 4 nodes/block, in staged to LDS.
// ===========================================================================
__global__ __launch_bounds__(256) void mix_kernel(
    const __half* __restrict__ in, int Cin, float* out, int Cout,
    const float* __restrict__ W, const float* __restrict__ bias,
    int accum, int V) {
    const int NPB = 4;
    __shared__ float in_s[NPB * 512];
    int t = threadIdx.x;
    int v0 = blockIdx.x * NPB;
    int BCin = 8 * Cin, BCout = 8 * Cout;
    for (int idx = t; idx < NPB * BCin; idx += 256) {
        int n = idx / BCin, r = idx - n * BCin;
        int v = v0 + n;
        in_s[idx] = (v < V) ? __half2float(in[(size_t)v * BCin + r]) : 0.f;
    }
    __syncthreads();
    for (int o = t; o < BCout; o += 256) {
        int b = o / Cout, co = o - b * Cout;
        float bb = bias ? bias[co] : 0.f;
        float a[NPB] = {bb, bb, bb, bb};
        for (int ci = 0; ci < Cin; ++ci) {
            float wv = W[ci * Cout + co];
            #pragma unroll
            for (int n = 0; n < NPB; ++n)
                a[n] += in_s[n * BCin + b * Cin + ci] * wv;
        }
        #pragma unroll
        for (int n = 0; n < NPB; ++n) {
            int v = v0 + n;
            if (v < V) {
                size_t oi = (size_t)v * BCout + o;
                float r = a[n];
                if (accum) r += out[oi];
                out[oi] = r;
            }
        }
    }
}

// ===========================================================================
// BatchNorm stats over fp16 or fp32 input
// ===========================================================================
__global__ void bn_stats_h_kernel(const __half* __restrict__ x, int C,
                                  float* __restrict__ sums, size_t N) {
    __shared__ float s_sum[256];
    __shared__ float s_sq[256];
    int t = threadIdx.x;
    size_t i0 = (size_t)blockIdx.x * 256 + t;
    size_t step = (size_t)gridDim.x * 256;
    float s = 0.f, q = 0.f;
    for (size_t i = i0; i < N; i += step) {
        float v = __half2float(x[i]);
        s += v; q += v * v;
    }
    s_sum[t] = s; s_sq[t] = q;
    __syncthreads();
    for (int st = 128; st >= C; st >>= 1) {
        if (t < st) { s_sum[t] += s_sum[t + st]; s_sq[t] += s_sq[t + st]; }
        __syncthreads();
    }
    if (t < C) {
        atomicAdd(&sums[t], s_sum[t]);
        atomicAdd(&sums[C + t], s_sq[t]);
    }
}

__global__ void bn_stats_f_kernel(const float* __restrict__ x, int C, int relu_in,
                                  float* __restrict__ sums, size_t N) {
    __shared__ float s_sum[256];
    __shared__ float s_sq[256];
    int t = threadIdx.x;
    size_t i0 = (size_t)blockIdx.x * 256 + t;
    size_t step = (size_t)gridDim.x * 256;
    float s = 0.f, q = 0.f;
    for (size_t i = i0; i < N; i += step) {
        float v = x[i];
        if (relu_in) v = fmaxf(v, 0.f);
        s += v; q += v * v;
    }
    s_sum[t] = s; s_sq[t] = q;
    __syncthreads();
    for (int st = 128; st >= C; st >>= 1) {
        if (t < st) { s_sum[t] += s_sum[t + st]; s_sq[t] += s_sq[t + st]; }
        __syncthreads();
    }
    if (t < C) {
        atomicAdd(&sums[t], s_sum[t]);
        atomicAdd(&sums[C + t], s_sq[t]);
    }
}

__global__ void bn_finalize_kernel(const float* __restrict__ sums, const float* __restrict__ g,
                                   const float* __restrict__ be, float* __restrict__ ss,
                                   int C, float invN) {
    int c = threadIdx.x;
    if (c < C) {
        float m = sums[c] * invN;
        float var = sums[C + c] * invN - m * m;
        float s = g[c] * rsqrtf(var + 1e-5f);
        ss[c] = s;
        ss[C + c] = be[c] - m * s;
    }
}

// in-place affine on fp16 features (x is a block input, already post-relu)
__global__ void affine_h_kernel(__half* x, const float* __restrict__ ss, int C, size_t N) {
    size_t stride = (size_t)gridDim.x * blockDim.x;
    for (size_t i = (size_t)blockIdx.x * blockDim.x + threadIdx.x; i < N; i += stride) {
        int c = (int)(i & (size_t)(C - 1));
        x[i] = __float2half(__half2float(x[i]) * ss[c] + ss[C + c]);
    }
}

// y = bn(relu(ACC)) -> fp16
__global__ void affine_f2h_kernel(const float* __restrict__ in, __half* __restrict__ out,
                                  const float* __restrict__ ss, int C, size_t N) {
    size_t stride = (size_t)gridDim.x * blockDim.x;
    for (size_t i = (size_t)blockIdx.x * blockDim.x + threadIdx.x; i < N; i += stride) {
        int c = (int)(i & (size_t)(C - 1));
        float v = fmaxf(in[i], 0.f);
        out[i] = __float2half(v * ss[c] + ss[C + c]);
    }
}

// x0 = relu(ACC + (add ? x0 : 0))   (fp16 out; x0 read-before-write per element)
__global__ void store_relu_kernel(const float* __restrict__ acc, __half* x0,
                                  int add, size_t N) {
    size_t stride = (size_t)gridDim.x * blockDim.x;
    for (size_t i = (size_t)blockIdx.x * blockDim.x + threadIdx.x; i < N; i += stride) {
        float r = acc[i];
        if (add) r += __half2float(x0[i]);
        x0[i] = __float2half(fmaxf(r, 0.f));
    }
}

// ===========================================================================
// head: max over nodes of relu(ACC) (m init 0 => implicit relu) + log_softmax
// ===========================================================================
__global__ void maxpool_kernel(const float* __restrict__ x, float* __restrict__ pooled, int V) {
    __shared__ float red[256];
    int o = blockIdx.x;     // 0..79 (b*10+co)
    float m = 0.f;
    for (int v = threadIdx.x; v < V; v += 256)
        m = fmaxf(m, x[(size_t)v * 80 + o]);
    red[threadIdx.x] = m;
    __syncthreads();
    for (int st = 128; st > 0; st >>= 1) {
        if (threadIdx.x < st) red[threadIdx.x] = fmaxf(red[threadIdx.x], red[threadIdx.x + st]);
        __syncthreads();
    }
    if (threadIdx.x == 0) pooled[o] = red[0];
}

// OUTPUT IS FP32 (reference output dtype is float32)
__global__ void lsm_kernel(const float* __restrict__ pooled, float* __restrict__ out) {
    int b = threadIdx.x;
    if (b < 8) {
        float m = -1e30f;
        for (int c = 0; c < 10; ++c) m = fmaxf(m, pooled[b * 10 + c]);
        float s = 0.f;
        for (int c = 0; c < 10; ++c) s += expf(pooled[b * 10 + c] - m);
        float l = logf(s);
        for (int c = 0; c < 10; ++c)
            out[b * 10 + c] = pooled[b * 10 + c] - m - l;
    }
}

// ws too small: report ws_size in MB via absmax (fp32 out)
__global__ void encode_kernel(float* out, float val) {
    int i = threadIdx.x;
    if (i < 80) out[i] = val;
}

// ===========================================================================
// entry
// ===========================================================================
extern "C" void kernel_launch(void* const* d_in, const int* in_sizes, int n_in,
                              void* d_out, int out_size, void* d_ws, size_t ws_size,
                              hipStream_t stream) {
    (void)in_sizes; (void)n_in; (void)out_size;
    const int V = 50000, E = 800000;

    auto al = [](size_t x) { return (x + 255) & ~(size_t)255; };
    const size_t ACCB = al((size_t)V * 512 * sizeof(float));      // 102.4 MB
    const size_t FB   = al((size_t)V * 512 * sizeof(__half));     // 51.2 MB
    const size_t need = ACCB + 3 * FB + al((V + 1) * 4) + al(V * 4) + al(E * 4) + al(E * 4)
                      + al(8 * 128 * 4) + al(8 * 128 * 4) + al(80 * 4);
    if (ws_size < need) {
        encode_kernel<<<1, 128, 0, stream>>>((float*)d_out, (float)(ws_size >> 20));
        return;
    }

    const float* x_in = (const float*)d_in[0];
    const int* rows   = (const int*)d_in[1];
    const int* colsi  = (const int*)d_in[2];
    const float* lvals = (const float*)d_in[3];
    const float* W_in = (const float*)d_in[4];
    const float* b_in = (const float*)d_in[5];
    const float* g1a = (const float*)d_in[6],  *be1a = (const float*)d_in[7];
    const float* W1a = (const float*)d_in[8],  *b1a  = (const float*)d_in[9];
    const float* g1b = (const float*)d_in[10], *be1b = (const float*)d_in[11];
    const float* W1b = (const float*)d_in[12], *b1b  = (const float*)d_in[13];
    const float* g2a = (const float*)d_in[14], *be2a = (const float*)d_in[15];
    const float* W2a = (const float*)d_in[16], *b2a  = (const float*)d_in[17];
    const float* g2b = (const float*)d_in[18], *be2b = (const float*)d_in[19];
    const float* W2b = (const float*)d_in[20], *b2b  = (const float*)d_in[21];
    const float* W2s = (const float*)d_in[22];
    const float* g3a = (const float*)d_in[23], *be3a = (const float*)d_in[24];
    const float* W3a = (const float*)d_in[25], *b3a  = (const float*)d_in[26];
    const float* g3b = (const float*)d_in[27], *be3b = (const float*)d_in[28];
    const float* W3b = (const float*)d_in[29], *b3b  = (const float*)d_in[30];
    const float* g_o = (const float*)d_in[31], *be_o = (const float*)d_in[32];
    const float* W_o = (const float*)d_in[33], *b_o  = (const float*)d_in[34];

    char* wp = (char*)d_ws;
    auto take = [&](size_t bytes) -> void* { void* p = (void*)wp; wp += al(bytes); return p; };
    float*  ACC = (float*)take((size_t)V * 512 * sizeof(float));
    __half* B0  = (__half*)take((size_t)V * 512 * sizeof(__half));
    __half* B1  = (__half*)take((size_t)V * 512 * sizeof(__half));
    __half* B2  = (__half*)take((size_t)V * 512 * sizeof(__half));
    int* row_ptr  = (int*)take((V + 1) * sizeof(int));
    int* cursor   = (int*)take(V * sizeof(int));
    int* cols_s   = (int*)take(E * sizeof(int));
    float* vals_s = (float*)take(E * sizeof(float));
    float* bn_sums = (float*)take(8 * 128 * sizeof(float));
    float* aff     = (float*)take(8 * 128 * sizeof(float));
    float* pooled  = (float*)take(80 * sizeof(float));

    // ---- CSR build + input transpose ----
    hipMemsetAsync(cursor, 0, V * sizeof(int), stream);
    hipMemsetAsync(bn_sums, 0, 8 * 128 * sizeof(float), stream);
    hist_kernel<<<(E + 255) / 256, 256, 0, stream>>>(rows, cursor, E);
    scan_kernel<<<1, 256, 0, stream>>>(cursor, row_ptr, V);
    init_cursor_kernel<<<(V + 255) / 256, 256, 0, stream>>>(row_ptr, cursor, V);
    scatter_kernel<<<(E + 255) / 256, 256, 0, stream>>>(rows, colsi, lvals, cursor, cols_s, vals_s, E);
    transpose_in_kernel<<<4096, 256, 0, stream>>>(x_in, B0, V);

    // ---- helpers ----
    auto spmm = [&](const __half* src, __half* dst, const __half* prev, int C) {
        spmm_kernel<<<V, 4 * C, 0, stream>>>(row_ptr, cols_s, vals_s,
                                             (const __half2*)src, (__half2*)dst,
                                             (const __half2*)prev);
    };
    auto mix = [&](const __half* in, int Cin, int Cout, const float* W,
                   const float* bias, int accum) {
        mix_kernel<<<(V + 3) / 4, 256, 0, stream>>>(in, Cin, ACC, Cout, W, bias, accum, V);
    };
    auto stats_h = [&](const __half* xb, int C, int slot, const float* g, const float* be) {
        bn_stats_h_kernel<<<1024, 256, 0, stream>>>(xb, C, bn_sums + slot * 128, (size_t)V * 8 * C);
        bn_finalize_kernel<<<1, 64, 0, stream>>>(bn_sums + slot * 128, g, be, aff + slot * 128, C,
                                                 1.f / ((float)V * 8.f));
    };
    auto stats_f = [&](const float* xb, int C, int relu, int slot, const float* g, const float* be) {
        bn_stats_f_kernel<<<1024, 256, 0, stream>>>(xb, C, relu, bn_sums + slot * 128, (size_t)V * 8 * C);
        bn_finalize_kernel<<<1, 64, 0, stream>>>(bn_sums + slot * 128, g, be, aff + slot * 128, C,
                                                 1.f / ((float)V * 8.f));
    };
    auto affine_h = [&](__half* xb, int C, int slot) {
        affine_h_kernel<<<2048, 256, 0, stream>>>(xb, aff + slot * 128, C, (size_t)V * 8 * C);
    };
    auto affine_f2h = [&](const float* in, __half* out, int C, int slot) {
        affine_f2h_kernel<<<2048, 256, 0, stream>>>(in, out, aff + slot * 128, C, (size_t)V * 8 * C);
    };
    auto store_relu = [&](int add, int C) {
        store_relu_kernel<<<2048, 256, 0, stream>>>(ACC, B0, add, (size_t)V * 8 * C);
    };
    // K=4 Chebyshev conv of xn (=B0, Cin ch) into ACC (Cout ch), using B1,B2.
    auto cheb_a = [&](int Cin, int Cout, const float* W, const float* bias) {
        mix(B0, Cin, Cout, W, bias, 0);                       // T0 = xn
        spmm(B0, B1, nullptr, Cin);                           // T1 = L xn
        mix(B1, Cin, Cout, W + 1 * Cin * Cout, nullptr, 1);
        spmm(B1, B2, B0, Cin);                                // T2 = 2 L T1 - xn
        mix(B2, Cin, Cout, W + 2 * Cin * Cout, nullptr, 1);
        spmm(B2, B1, B1, Cin);                                // T3 = 2 L T2 - T1
        mix(B1, Cin, Cout, W + 3 * Cin * Cout, nullptr, 1);
    };
    // same but input y = B1, scratch B2 (B0 preserved = xn for shortcut)
    auto cheb_b = [&](int C, const float* W, const float* bias) {
        mix(B1, C, C, W, bias, 0);                            // T0 = y (overwrites ACC)
        spmm(B1, B2, nullptr, C);                             // T1 = L y
        mix(B2, C, C, W + 1 * C * C, nullptr, 1);
        spmm(B2, B1, B1, C);                                  // T2 = 2 L T1 - y
        mix(B1, C, C, W + 2 * C * C, nullptr, 1);
        spmm(B1, B2, B2, C);                                  // T3 = 2 L T2 - T1
        mix(B2, C, C, W + 3 * C * C, nullptr, 1);
    };

    // ---- conv_in: x(16ch, B0) -> relu(cheb+b) -> B0 (32ch) ----
    cheb_a(16, 32, W_in, b_in);
    store_relu(0, 32);

    // ---- block 1: 32 -> 32, identity shortcut ----
    stats_h(B0, 32, 0, g1a, be1a);
    affine_h(B0, 32, 0);                    // B0 = xn
    cheb_a(32, 32, W1a, b1a);               // ACC = out_a
    stats_f(ACC, 32, 1, 1, g1b, be1b);
    affine_f2h(ACC, B1, 32, 1);             // B1 = y = bn(relu(out_a))
    cheb_b(32, W1b, b1b);                   // ACC = conv_b(y)
    store_relu(1, 32);                      // B0 = relu(ACC + xn)

    // ---- block 2: 32 -> 64, W2s shortcut ----
    stats_h(B0, 32, 2, g2a, be2a);
    affine_h(B0, 32, 2);                    // B0 = xn (32ch)
    cheb_a(32, 64, W2a, b2a);               // ACC = out_a (64ch)
    stats_f(ACC, 64, 1, 3, g2b, be2b);
    affine_f2h(ACC, B1, 64, 3);             // B1 = y (64ch)
    cheb_b(64, W2b, b2b);                   // ACC = conv_b(y)
    mix(B0, 32, 64, W2s, nullptr, 1);       // ACC += xn @ W2s
    store_relu(0, 64);                      // B0 = relu(ACC) (64ch)

    // ---- block 3: 64 -> 64, identity shortcut ----
    stats_h(B0, 64, 4, g3a, be3a);
    affine_h(B0, 64, 4);                    // B0 = xn
    cheb_a(64, 64, W3a, b3a);
    stats_f(ACC, 64, 1, 5, g3b, be3b);
    affine_f2h(ACC, B1, 64, 5);             // B1 = y
    cheb_b(64, W3b, b3b);
    store_relu(1, 64);                      // B0 = relu(ACC + xn)

    // ---- head: bn -> cheb(64->10) -> relu(max-pool) -> log_softmax ----
    stats_h(B0, 64, 6, g_o, be_o);
    affine_h(B0, 64, 6);                    // B0 = bn(x)
    cheb_a(64, 10, W_o, b_o);               // ACC = logits per node (80 wide)
    maxpool_kernel<<<80, 256, 0, stream>>>(ACC, pooled, V);   // implicit relu (m init 0)
    lsm_kernel<<<1, 64, 0, stream>>>(pooled, (float*)d_out);
}

// Round 7
// 4971.351 us; speedup vs baseline: 1.6369x; 1.6369x over previous
//
#include <hip/hip_runtime.h>
#include <hip/hip_bf16.h>
#include <hip/hip_fp16.h>

// ===========================================================================
// CSR build
// ===========================================================================
__global__ void hist_kernel(const int* __restrict__ rows, int* __restrict__ counts, int E) {
    int i = blockIdx.x * blockDim.x + threadIdx.x;
    if (i < E) atomicAdd(&counts[rows[i]], 1);
}

__global__ void scan_kernel(const int* __restrict__ counts, int* __restrict__ row_ptr, int V) {
    __shared__ int wsum[4];
    __shared__ int s_carry;
    int t = threadIdx.x;           // 256 threads
    int lane = t & 63, w = t >> 6;
    if (t == 0) { s_carry = 0; row_ptr[0] = 0; }
    __syncthreads();
    for (int base = 0; base < V; base += 256) {
        int i = base + t;
        int x = (i < V) ? counts[i] : 0;
        #pragma unroll
        for (int d = 1; d < 64; d <<= 1) {
            int y = __shfl_up(x, d);
            if (lane >= d) x += y;
        }
        if (lane == 63) wsum[w] = x;
        __syncthreads();
        int wo = 0;
        for (int j = 0; j < w; ++j) wo += wsum[j];
        int total = wsum[0] + wsum[1] + wsum[2] + wsum[3];
        if (i < V) row_ptr[i + 1] = s_carry + wo + x;
        __syncthreads();
        if (t == 0) s_carry += total;
        __syncthreads();
    }
}

__global__ void init_cursor_kernel(const int* __restrict__ row_ptr, int* __restrict__ cursor, int V) {
    int i = blockIdx.x * blockDim.x + threadIdx.x;
    if (i < V) cursor[i] = row_ptr[i];
}

__global__ void scatter_kernel(const int* __restrict__ rows, const int* __restrict__ cols,
                               const float* __restrict__ vals, int* __restrict__ cursor,
                               int* __restrict__ cols_s, float* __restrict__ vals_s, int E) {
    int i = blockIdx.x * blockDim.x + threadIdx.x;
    if (i < E) {
        int r = rows[i];
        int p = atomicAdd(&cursor[r], 1);
        cols_s[p] = cols[i];
        vals_s[p] = vals[i];
    }
}

// ===========================================================================
// transpose input (B,16,V) fp32 -> (V, B*16) fp16.  i = v*128 + (b*16+c)
// ===========================================================================
__global__ void transpose_in_kernel(const float* __restrict__ x, __half* __restrict__ X, int V) {
    int total = V * 128;
    for (int i = blockIdx.x * blockDim.x + threadIdx.x; i < total; i += gridDim.x * blockDim.x) {
        int v = i >> 7;
        int t = i & 127;          // t = b*16 + c
        X[i] = __float2half(x[t * V + v]);
    }
}

// ===========================================================================
// SpMM v2: one wave per node, lane owns a contiguous VPT*4-byte chunk.
// Edge loop unrolled x4 with all gathers in flight (ILP fix for VGPR=8 /
// VALUBusy=5% latency-bound round-6 kernel).
//   dst[v,:] = sum_e vals[e]*src[cols[e],:]          (prev == null)
//   dst[v,:] = 2*that - prev[v,:]                    (prev != null)
// prev may alias dst (same-thread read-before-write).
// VPT: half2 per lane. C=16 -> 1, C=32 -> 2, C=64 -> 4.
// ===========================================================================
template <int VPT> struct PackT;
template <> struct PackT<1> { using T = float;  };
template <> struct PackT<2> { using T = float2; };
template <> struct PackT<4> { using T = float4; };

template <int VPT>
__global__ __launch_bounds__(256) void spmm2_kernel(
    const int* __restrict__ row_ptr, const int* __restrict__ cols,
    const float* __restrict__ vals, const __half2* __restrict__ src,
    __half2* dst, const __half2* prev, int V) {
    using T = typename PackT<VPT>::T;
    union U { T raw; __half2 h[VPT]; };
    int lane = threadIdx.x & 63;
    int v = (blockIdx.x << 2) | (threadIdx.x >> 6);
    if (v >= V) return;
    const int W = VPT * 64;                       // half2 per node row
    const size_t row = (size_t)v * W + lane * VPT;

    float pr[2 * VPT];
    bool hasp = (prev != nullptr);
    if (hasp) {
        U pv; pv.raw = *(const T*)(prev + row);   // load BEFORE any store
        #pragma unroll
        for (int j = 0; j < VPT; ++j) {
            float2 f = __half22float2(pv.h[j]);
            pr[2 * j] = f.x; pr[2 * j + 1] = f.y;
        }
    }
    float acc[2 * VPT];
    #pragma unroll
    for (int j = 0; j < 2 * VPT; ++j) acc[j] = 0.f;

    int e0 = row_ptr[v], e1 = row_ptr[v + 1];
    int e = e0;
    for (; e + 4 <= e1; e += 4) {
        int   c0 = cols[e],   c1 = cols[e + 1], c2 = cols[e + 2], c3 = cols[e + 3];
        float w0 = vals[e],   w1 = vals[e + 1], w2 = vals[e + 2], w3 = vals[e + 3];
        U g0, g1, g2, g3;
        g0.raw = *(const T*)(src + (size_t)c0 * W + lane * VPT);
        g1.raw = *(const T*)(src + (size_t)c1 * W + lane * VPT);
        g2.raw = *(const T*)(src + (size_t)c2 * W + lane * VPT);
        g3.raw = *(const T*)(src + (size_t)c3 * W + lane * VPT);
        #pragma unroll
        for (int j = 0; j < VPT; ++j) {
            float2 f;
            f = __half22float2(g0.h[j]); acc[2*j] += w0 * f.x; acc[2*j+1] += w0 * f.y;
            f = __half22float2(g1.h[j]); acc[2*j] += w1 * f.x; acc[2*j+1] += w1 * f.y;
            f = __half22float2(g2.h[j]); acc[2*j] += w2 * f.x; acc[2*j+1] += w2 * f.y;
            f = __half22float2(g3.h[j]); acc[2*j] += w3 * f.x; acc[2*j+1] += w3 * f.y;
        }
    }
    for (; e < e1; ++e) {
        int c = cols[e]; float wv = vals[e];
        U g; g.raw = *(const T*)(src + (size_t)c * W + lane * VPT);
        #pragma unroll
        for (int j = 0; j < VPT; ++j) {
            float2 f = __half22float2(g.h[j]);
            acc[2*j] += wv * f.x; acc[2*j+1] += wv * f.y;
        }
    }
    if (hasp) {
        #pragma unroll
        for (int j = 0; j < 2 * VPT; ++j) acc[j] = 2.f * acc[j] - pr[j];
    }
    U o;
    #pragma unroll
    for (int j = 0; j < VPT; ++j) o.h[j] = __floats2half2_rn(acc[2*j], acc[2*j+1]);
    *(T*)(dst + row) = o.raw;
}

// ===========================================================================
// mix v2 (Cout in {32,64}): register-blocked GEMM.
// Thread computes 4 nodes x 8 output cols (32 fp32 accumulators).
// LDS input tile laid out [group][b][ci][node(4)] with +4-float row pad
// (conflict-free ds_read_b128); W tile staged to LDS.
// out (fp32 ACC) (+)= in(fp16) @ W (+bias)
// ===========================================================================
__global__ __launch_bounds__(256) void mix2_kernel(
    const __half* __restrict__ in, int Cin, float* out, int Cout,
    const float* __restrict__ Wg, const float* __restrict__ bias,
    int accum, int V) {
    extern __shared__ float lds[];
    const int G  = 256 / Cout;        // 4-node groups per block
    const int NB = 4 * G;             // nodes per block
    const int RS = 4 * Cin + 4;       // padded floats per (g,b) row
    const int BCin = 8 * Cin, BCout = 8 * Cout;
    float* ins = lds;                 // G*8*RS floats
    float* Ws  = lds + G * 8 * RS;    // Cin*Cout floats

    int tid = threadIdx.x;
    int v0 = blockIdx.x * NB;

    // ---- stage W ----
    for (int idx = tid; idx < (Cin * Cout) / 4; idx += 256)
        *(float4*)(Ws + idx * 4) = *(const float4*)(Wg + idx * 4);
    // ---- stage inputs (half2 pairs) ----
    int total = NB * BCin;
    for (int idx = tid; idx * 2 < total; idx += 256) {
        int p = idx * 2;
        int n = p / BCin, r = p - n * BCin;         // r even, pair in same row
        int vv = v0 + n;
        float2 f = make_float2(0.f, 0.f);
        if (vv < V) f = __half22float2(*(const __half2*)(in + (size_t)vv * BCin + r));
        int b = r / Cin, ci = r - b * Cin;          // ci even, ci+1 same b
        int g = n >> 2, j = n & 3;
        float* base = ins + (g * 8 + b) * RS + j;
        base[ci * 4]       = f.x;
        base[(ci + 1) * 4] = f.y;
    }
    __syncthreads();

    // ---- compute: thread -> (g, b, cog) ----
    int g   = tid / Cout;
    int u   = tid - g * Cout;
    int CO8 = Cout >> 3;
    int b   = u / CO8;
    int co0 = (u - b * CO8) * 8;

    float a[4][8];
    #pragma unroll
    for (int n = 0; n < 4; ++n)
        #pragma unroll
        for (int k = 0; k < 8; ++k) a[n][k] = 0.f;

    const float* ib = ins + (g * 8 + b) * RS;
    for (int ci = 0; ci < Cin; ++ci) {
        float4 x  = *(const float4*)(ib + ci * 4);
        float4 w0 = *(const float4*)(Ws + ci * Cout + co0);
        float4 w1 = *(const float4*)(Ws + ci * Cout + co0 + 4);
        float xv[4] = {x.x, x.y, x.z, x.w};
        float wv[8] = {w0.x, w0.y, w0.z, w0.w, w1.x, w1.y, w1.z, w1.w};
        #pragma unroll
        for (int n = 0; n < 4; ++n)
            #pragma unroll
            for (int k = 0; k < 8; ++k)
                a[n][k] = fmaf(xv[n], wv[k], a[n][k]);
    }

    float bb[8];
    #pragma unroll
    for (int k = 0; k < 8; ++k) bb[k] = bias ? bias[co0 + k] : 0.f;

    #pragma unroll
    for (int n = 0; n < 4; ++n) {
        int vv = v0 + g * 4 + n;
        if (vv < V) {
            size_t oo = (size_t)vv * BCout + b * Cout + co0;
            float4 r0 = make_float4(a[n][0] + bb[0], a[n][1] + bb[1],
                                    a[n][2] + bb[2], a[n][3] + bb[3]);
            float4 r1 = make_float4(a[n][4] + bb[4], a[n][5] + bb[5],
                                    a[n][6] + bb[6], a[n][7] + bb[7]);
            if (accum) {
                float4 o0 = *(const float4*)(out + oo);
                float4 o1 = *(const float4*)(out + oo + 4);
                r0.x += o0.x; r0.y += o0.y; r0.z += o0.z; r0.w += o0.w;
                r1.x += o1.x; r1.y += o1.y; r1.z += o1.z; r1.w += o1.w;
            }
            *(float4*)(out + oo)     = r0;
            *(float4*)(out + oo + 4) = r1;
        }
    }
}

// ===========================================================================
// mix (simple; kept for Cout=10 head): ACC (+)= in @ W (+bias)
// ===========================================================================
__global__ __launch_bounds__(256) void mix_kernel(
    const __half* __restrict__ in, int Cin, float* out, int Cout,
    const float* __restrict__ W, const float* __restrict__ bias,
    int accum, int V) {
    const int NPB = 4;
    __shared__ float in_s[NPB * 512];
    int t = threadIdx.x;
    int v0 = blockIdx.x * NPB;
    int BCin = 8 * Cin, BCout = 8 * Cout;
    for (int idx = t; idx < NPB * BCin; idx += 256) {
        int n = idx / BCin, r = idx - n * BCin;
        int v = v0 + n;
        in_s[idx] = (v < V) ? __half2float(in[(size_t)v * BCin + r]) : 0.f;
    }
    __syncthreads();
    for (int o = t; o < BCout; o += 256) {
        int b = o / Cout, co = o - b * Cout;
        float bb = bias ? bias[co] : 0.f;
        float a[NPB] = {bb, bb, bb, bb};
        for (int ci = 0; ci < Cin; ++ci) {
            float wv = W[ci * Cout + co];
            #pragma unroll
            for (int n = 0; n < NPB; ++n)
                a[n] += in_s[n * BCin + b * Cin + ci] * wv;
        }
        #pragma unroll
        for (int n = 0; n < NPB; ++n) {
            int v = v0 + n;
            if (v < V) {
                size_t oi = (size_t)v * BCout + o;
                float r = a[n];
                if (accum) r += out[oi];
                out[oi] = r;
            }
        }
    }
}

// ===========================================================================
// BatchNorm stats over fp16 or fp32 input
// ===========================================================================
__global__ void bn_stats_h_kernel(const __half* __restrict__ x, int C,
                                  float* __restrict__ sums, size_t N) {
    __shared__ float s_sum[256];
    __shared__ float s_sq[256];
    int t = threadIdx.x;
    size_t i0 = (size_t)blockIdx.x * 256 + t;
    size_t step = (size_t)gridDim.x * 256;
    float s = 0.f, q = 0.f;
    for (size_t i = i0; i < N; i += step) {
        float v = __half2float(x[i]);
        s += v; q += v * v;
    }
    s_sum[t] = s; s_sq[t] = q;
    __syncthreads();
    for (int st = 128; st >= C; st >>= 1) {
        if (t < st) { s_sum[t] += s_sum[t + st]; s_sq[t] += s_sq[t + st]; }
        __syncthreads();
    }
    if (t < C) {
        atomicAdd(&sums[t], s_sum[t]);
        atomicAdd(&sums[C + t], s_sq[t]);
    }
}

__global__ void bn_stats_f_kernel(const float* __restrict__ x, int C, int relu_in,
                                  float* __restrict__ sums, size_t N) {
    __shared__ float s_sum[256];
    __shared__ float s_sq[256];
    int t = threadIdx.x;
    size_t i0 = (size_t)blockIdx.x * 256 + t;
    size_t step = (size_t)gridDim.x * 256;
    float s = 0.f, q = 0.f;
    for (size_t i = i0; i < N; i += step) {
        float v = x[i];
        if (relu_in) v = fmaxf(v, 0.f);
        s += v; q += v * v;
    }
    s_sum[t] = s; s_sq[t] = q;
    __syncthreads();
    for (int st = 128; st >= C; st >>= 1) {
        if (t < st) { s_sum[t] += s_sum[t + st]; s_sq[t] += s_sq[t + st]; }
        __syncthreads();
    }
    if (t < C) {
        atomicAdd(&sums[t], s_sum[t]);
        atomicAdd(&sums[C + t], s_sq[t]);
    }
}

__global__ void bn_finalize_kernel(const float* __restrict__ sums, const float* __restrict__ g,
                                   const float* __restrict__ be, float* __restrict__ ss,
                                   int C, float invN) {
    int c = threadIdx.x;
    if (c < C) {
        float m = sums[c] * invN;
        float var = sums[C + c] * invN - m * m;
        float s = g[c] * rsqrtf(var + 1e-5f);
        ss[c] = s;
        ss[C + c] = be[c] - m * s;
    }
}

// in-place affine on fp16 features
__global__ void affine_h_kernel(__half* x, const float* __restrict__ ss, int C, size_t N) {
    size_t stride = (size_t)gridDim.x * blockDim.x;
    for (size_t i = (size_t)blockIdx.x * blockDim.x + threadIdx.x; i < N; i += stride) {
        int c = (int)(i & (size_t)(C - 1));
        x[i] = __float2half(__half2float(x[i]) * ss[c] + ss[C + c]);
    }
}

// y = bn(relu(ACC)) -> fp16
__global__ void affine_f2h_kernel(const float* __restrict__ in, __half* __restrict__ out,
                                  const float* __restrict__ ss, int C, size_t N) {
    size_t stride = (size_t)gridDim.x * blockDim.x;
    for (size_t i = (size_t)blockIdx.x * blockDim.x + threadIdx.x; i < N; i += stride) {
        int c = (int)(i & (size_t)(C - 1));
        float v = fmaxf(in[i], 0.f);
        out[i] = __float2half(v * ss[c] + ss[C + c]);
    }
}

// x0 = relu(ACC + (add ? x0 : 0))
__global__ void store_relu_kernel(const float* __restrict__ acc, __half* x0,
                                  int add, size_t N) {
    size_t stride = (size_t)gridDim.x * blockDim.x;
    for (size_t i = (size_t)blockIdx.x * blockDim.x + threadIdx.x; i < N; i += stride) {
        float r = acc[i];
        if (add) r += __half2float(x0[i]);
        x0[i] = __float2half(fmaxf(r, 0.f));
    }
}

// ===========================================================================
// head: max over nodes of relu(ACC) (m init 0 => implicit relu) + log_softmax
// ===========================================================================
__global__ void maxpool_kernel(const float* __restrict__ x, float* __restrict__ pooled, int V) {
    __shared__ float red[256];
    int o = blockIdx.x;     // 0..79 (b*10+co)
    float m = 0.f;
    for (int v = threadIdx.x; v < V; v += 256)
        m = fmaxf(m, x[(size_t)v * 80 + o]);
    red[threadIdx.x] = m;
    __syncthreads();
    for (int st = 128; st > 0; st >>= 1) {
        if (threadIdx.x < st) red[threadIdx.x] = fmaxf(red[threadIdx.x], red[threadIdx.x + st]);
        __syncthreads();
    }
    if (threadIdx.x == 0) pooled[o] = red[0];
}

// OUTPUT IS FP32 (reference output dtype is float32)
__global__ void lsm_kernel(const float* __restrict__ pooled, float* __restrict__ out) {
    int b = threadIdx.x;
    if (b < 8) {
        float m = -1e30f;
        for (int c = 0; c < 10; ++c) m = fmaxf(m, pooled[b * 10 + c]);
        float s = 0.f;
        for (int c = 0; c < 10; ++c) s += expf(pooled[b * 10 + c] - m);
        float l = logf(s);
        for (int c = 0; c < 10; ++c)
            out[b * 10 + c] = pooled[b * 10 + c] - m - l;
    }
}

// ws too small: report ws_size in MB via absmax (fp32 out)
__global__ void encode_kernel(float* out, float val) {
    int i = threadIdx.x;
    if (i < 80) out[i] = val;
}

// ===========================================================================
// entry
// ===========================================================================
extern "C" void kernel_launch(void* const* d_in, const int* in_sizes, int n_in,
                              void* d_out, int out_size, void* d_ws, size_t ws_size,
                              hipStream_t stream) {
    (void)in_sizes; (void)n_in; (void)out_size;
    const int V = 50000, E = 800000;

    auto al = [](size_t x) { return (x + 255) & ~(size_t)255; };
    const size_t ACCB = al((size_t)V * 512 * sizeof(float));      // 102.4 MB
    const size_t FB   = al((size_t)V * 512 * sizeof(__half));     // 51.2 MB
    const size_t need = ACCB + 3 * FB + al((V + 1) * 4) + al(V * 4) + al(E * 4) + al(E * 4)
                      + al(8 * 128 * 4) + al(8 * 128 * 4) + al(80 * 4);
    if (ws_size < need) {
        encode_kernel<<<1, 128, 0, stream>>>((float*)d_out, (float)(ws_size >> 20));
        return;
    }

    const float* x_in = (const float*)d_in[0];
    const int* rows   = (const int*)d_in[1];
    const int* colsi  = (const int*)d_in[2];
    const float* lvals = (const float*)d_in[3];
    const float* W_in = (const float*)d_in[4];
    const float* b_in = (const float*)d_in[5];
    const float* g1a = (const float*)d_in[6],  *be1a = (const float*)d_in[7];
    const float* W1a = (const float*)d_in[8],  *b1a  = (const float*)d_in[9];
    const float* g1b = (const float*)d_in[10], *be1b = (const float*)d_in[11];
    const float* W1b = (const float*)d_in[12], *b1b  = (const float*)d_in[13];
    const float* g2a = (const float*)d_in[14], *be2a = (const float*)d_in[15];
    const float* W2a = (const float*)d_in[16], *b2a  = (const float*)d_in[17];
    const float* g2b = (const float*)d_in[18], *be2b = (const float*)d_in[19];
    const float* W2b = (const float*)d_in[20], *b2b  = (const float*)d_in[21];
    const float* W2s = (const float*)d_in[22];
    const float* g3a = (const float*)d_in[23], *be3a = (const float*)d_in[24];
    const float* W3a = (const float*)d_in[25], *b3a  = (const float*)d_in[26];
    const float* g3b = (const float*)d_in[27], *be3b = (const float*)d_in[28];
    const float* W3b = (const float*)d_in[29], *b3b  = (const float*)d_in[30];
    const float* g_o = (const float*)d_in[31], *be_o = (const float*)d_in[32];
    const float* W_o = (const float*)d_in[33], *b_o  = (const float*)d_in[34];

    char* wp = (char*)d_ws;
    auto take = [&](size_t bytes) -> void* { void* p = (void*)wp; wp += al(bytes); return p; };
    float*  ACC = (float*)take((size_t)V * 512 * sizeof(float));
    __half* B0  = (__half*)take((size_t)V * 512 * sizeof(__half));
    __half* B1  = (__half*)take((size_t)V * 512 * sizeof(__half));
    __half* B2  = (__half*)take((size_t)V * 512 * sizeof(__half));
    int* row_ptr  = (int*)take((V + 1) * sizeof(int));
    int* cursor   = (int*)take(V * sizeof(int));
    int* cols_s   = (int*)take(E * sizeof(int));
    float* vals_s = (float*)take(E * sizeof(float));
    float* bn_sums = (float*)take(8 * 128 * sizeof(float));
    float* aff     = (float*)take(8 * 128 * sizeof(float));
    float* pooled  = (float*)take(80 * sizeof(float));

    // ---- CSR build + input transpose ----
    hipMemsetAsync(cursor, 0, V * sizeof(int), stream);
    hipMemsetAsync(bn_sums, 0, 8 * 128 * sizeof(float), stream);
    hist_kernel<<<(E + 255) / 256, 256, 0, stream>>>(rows, cursor, E);
    scan_kernel<<<1, 256, 0, stream>>>(cursor, row_ptr, V);
    init_cursor_kernel<<<(V + 255) / 256, 256, 0, stream>>>(row_ptr, cursor, V);
    scatter_kernel<<<(E + 255) / 256, 256, 0, stream>>>(rows, colsi, lvals, cursor, cols_s, vals_s, E);
    transpose_in_kernel<<<4096, 256, 0, stream>>>(x_in, B0, V);

    // ---- helpers ----
    auto spmm = [&](const __half* src, __half* dst, const __half* prev, int C) {
        int grid = (V + 3) / 4;
        if (C == 16)
            spmm2_kernel<1><<<grid, 256, 0, stream>>>(row_ptr, cols_s, vals_s,
                (const __half2*)src, (__half2*)dst, (const __half2*)prev, V);
        else if (C == 32)
            spmm2_kernel<2><<<grid, 256, 0, stream>>>(row_ptr, cols_s, vals_s,
                (const __half2*)src, (__half2*)dst, (const __half2*)prev, V);
        else
            spmm2_kernel<4><<<grid, 256, 0, stream>>>(row_ptr, cols_s, vals_s,
                (const __half2*)src, (__half2*)dst, (const __half2*)prev, V);
    };
    auto mix = [&](const __half* in, int Cin, int Cout, const float* W,
                   const float* bias, int accum) {
        if (Cout == 32 || Cout == 64) {
            int G = 256 / Cout, NB = 4 * G, RS = 4 * Cin + 4;
            size_t ldsb = (size_t)(G * 8 * RS + Cin * Cout) * sizeof(float);
            mix2_kernel<<<(V + NB - 1) / NB, 256, ldsb, stream>>>(in, Cin, ACC, Cout,
                                                                  W, bias, accum, V);
        } else {
            mix_kernel<<<(V + 3) / 4, 256, 0, stream>>>(in, Cin, ACC, Cout, W, bias, accum, V);
        }
    };
    auto stats_h = [&](const __half* xb, int C, int slot, const float* g, const float* be) {
        bn_stats_h_kernel<<<1024, 256, 0, stream>>>(xb, C, bn_sums + slot * 128, (size_t)V * 8 * C);
        bn_finalize_kernel<<<1, 64, 0, stream>>>(bn_sums + slot * 128, g, be, aff + slot * 128, C,
                                                 1.f / ((float)V * 8.f));
    };
    auto stats_f = [&](const float* xb, int C, int relu, int slot, const float* g, const float* be) {
        bn_stats_f_kernel<<<1024, 256, 0, stream>>>(xb, C, relu, bn_sums + slot * 128, (size_t)V * 8 * C);
        bn_finalize_kernel<<<1, 64, 0, stream>>>(bn_sums + slot * 128, g, be, aff + slot * 128, C,
                                                 1.f / ((float)V * 8.f));
    };
    auto affine_h = [&](__half* xb, int C, int slot) {
        affine_h_kernel<<<2048, 256, 0, stream>>>(xb, aff + slot * 128, C, (size_t)V * 8 * C);
    };
    auto affine_f2h = [&](const float* in, __half* out, int C, int slot) {
        affine_f2h_kernel<<<2048, 256, 0, stream>>>(in, out, aff + slot * 128, C, (size_t)V * 8 * C);
    };
    auto store_relu = [&](int add, int C) {
        store_relu_kernel<<<2048, 256, 0, stream>>>(ACC, B0, add, (size_t)V * 8 * C);
    };
    // K=4 Chebyshev conv of xn (=B0, Cin ch) into ACC (Cout ch), using B1,B2.
    auto cheb_a = [&](int Cin, int Cout, const float* W, const float* bias) {
        mix(B0, Cin, Cout, W, bias, 0);                       // T0 = xn
        spmm(B0, B1, nullptr, Cin);                           // T1 = L xn
        mix(B1, Cin, Cout, W + 1 * Cin * Cout, nullptr, 1);
        spmm(B1, B2, B0, Cin);                                // T2 = 2 L T1 - xn
        mix(B2, Cin, Cout, W + 2 * Cin * Cout, nullptr, 1);
        spmm(B2, B1, B1, Cin);                                // T3 = 2 L T2 - T1
        mix(B1, Cin, Cout, W + 3 * Cin * Cout, nullptr, 1);
    };
    // same but input y = B1, scratch B2 (B0 preserved = xn for shortcut)
    auto cheb_b = [&](int C, const float* W, const float* bias) {
        mix(B1, C, C, W, bias, 0);                            // T0 = y (overwrites ACC)
        spmm(B1, B2, nullptr, C);                             // T1 = L y
        mix(B2, C, C, W + 1 * C * C, nullptr, 1);
        spmm(B2, B1, B1, C);                                  // T2 = 2 L T1 - y
        mix(B1, C, C, W + 2 * C * C, nullptr, 1);
        spmm(B1, B2, B2, C);                                  // T3 = 2 L T2 - T1
        mix(B2, C, C, W + 3 * C * C, nullptr, 1);
    };

    // ---- conv_in: x(16ch, B0) -> relu(cheb+b) -> B0 (32ch) ----
    cheb_a(16, 32, W_in, b_in);
    store_relu(0, 32);

    // ---- block 1: 32 -> 32, identity shortcut ----
    stats_h(B0, 32, 0, g1a, be1a);
    affine_h(B0, 32, 0);                    // B0 = xn
    cheb_a(32, 32, W1a, b1a);               // ACC = out_a
    stats_f(ACC, 32, 1, 1, g1b, be1b);
    affine_f2h(ACC, B1, 32, 1);             // B1 = y = bn(relu(out_a))
    cheb_b(32, W1b, b1b);                   // ACC = conv_b(y)
    store_relu(1, 32);                      // B0 = relu(ACC + xn)

    // ---- block 2: 32 -> 64, W2s shortcut ----
    stats_h(B0, 32, 2, g2a, be2a);
    affine_h(B0, 32, 2);                    // B0 = xn (32ch)
    cheb_a(32, 64, W2a, b2a);               // ACC = out_a (64ch)
    stats_f(ACC, 64, 1, 3, g2b, be2b);
    affine_f2h(ACC, B1, 64, 3);             // B1 = y (64ch)
    cheb_b(64, W2b, b2b);                   // ACC = conv_b(y)
    mix(B0, 32, 64, W2s, nullptr, 1);       // ACC += xn @ W2s
    store_relu(0, 64);                      // B0 = relu(ACC) (64ch)

    // ---- block 3: 64 -> 64, identity shortcut ----
    stats_h(B0, 64, 4, g3a, be3a);
    affine_h(B0, 64, 4);                    // B0 = xn
    cheb_a(64, 64, W3a, b3a);
    stats_f(ACC, 64, 1, 5, g3b, be3b);
    affine_f2h(ACC, B1, 64, 5);             // B1 = y
    cheb_b(64, W3b, b3b);
    store_relu(1, 64);                      // B0 = relu(ACC + xn)

    // ---- head: bn -> cheb(64->10) -> relu(max-pool) -> log_softmax ----
    stats_h(B0, 64, 6, g_o, be_o);
    affine_h(B0, 64, 6);                    // B0 = bn(x)
    cheb_a(64, 10, W_o, b_o);               // ACC = logits per node (80 wide)
    maxpool_kernel<<<80, 256, 0, stream>>>(ACC, pooled, V);   // implicit relu (m init 0)
    lsm_kernel<<<1, 64, 0, stream>>>(pooled, (float*)d_out);
}